// Round 3
// baseline (11064.096 us; speedup 1.0000x reference)
//
#include <hip/hip_runtime.h>
#include <math.h>

#define LN2F 0.69314718055994530942f
#define PI_F 3.14159265358979323846f
constexpr float DMU = 4.0f/49.0f;          // gaussian spacing, linspace(0,4,50)
constexpr float GC  = -0.5f/(DMU*DMU);     // smearing coeff

__device__ __forceinline__ float sspf(float x){
  return fmaxf(x, 0.f) + log1pf(expf(-fabsf(x))) - LN2F;
}
__device__ __forceinline__ float sigf(float x){ return 1.f/(1.f+expf(-x)); }

// ---------------------------------------------------------------------------
// Generic fp32 GEMM: out[M,NN] = epi( A'[M,KK] @ B[KK,NN] )
//  A' transform: ATR 0=none 1=ssp 2=A*sigmoid(aux[r,k]) 3=auxvec[k]*sigmoid(A)
//                4=gaussian-smearing from w-vector aux[r] (A unused)
//  B: TRB=false -> B[k][n]=Bsrc[k*NN+n] (k<Kreal else 0)
//     TRB=true  -> B[k][n]=Bsrc[n*KK+k] (n<Nreal else 0)
//  epi: +bias[n] (BIAS), OTR 1=ssp, 2= *sigmoid(oaux[r,n]), RES: +res[r,n]
// ---------------------------------------------------------------------------
template<int KK,int NN,bool TRB,int ATR,bool BIAS,int OTR,bool RES>
__global__ __launch_bounds__(256) void gemm_k(
    const float* __restrict__ A, int lda,
    const float* __restrict__ aux, const float* __restrict__ auxvec,
    const float* __restrict__ B, int Kreal, int Nreal,
    const float* __restrict__ bias, const float* __restrict__ res,
    const float* __restrict__ oaux, float* __restrict__ out, int M)
{
  constexpr int TM = 128, BK = 32;
  constexpr int TX = (NN==128)?16:8;
  constexpr int RT = (NN==128)?8:4;
  __shared__ float As[BK][TM+4];
  __shared__ float Bs[BK][NN+4];
  const int t = threadIdx.x;
  const int tx = t % TX, ty = t / TX;
  const int m0 = blockIdx.x * TM;
  float acc[RT][8];
  #pragma unroll
  for (int i=0;i<RT;i++)
    #pragma unroll
    for (int j=0;j<8;j++) acc[i][j]=0.f;

  for (int kc=0; kc<KK; kc+=BK){
    // ---- stage A tile [128 x 32] ----
    #pragma unroll
    for (int j=0;j<4;j++){
      int p = t + j*256;
      int m = p >> 3;
      int kv = (p & 7) << 2;
      float4 v = make_float4(0.f,0.f,0.f,0.f);
      if (m0+m < M){
        if constexpr (ATR==4){
          float wm = aux[m0+m];
          #pragma unroll
          for (int q=0;q<4;q++){
            int k = kc+kv+q;
            float d = wm - (float)k*DMU;
            ((float*)&v)[q] = (k<50) ? expf(GC*d*d) : 0.f;
          }
        } else {
          v = *(const float4*)(A + (size_t)(m0+m)*lda + kc + kv);
          if constexpr (ATR==1){ v.x=sspf(v.x); v.y=sspf(v.y); v.z=sspf(v.z); v.w=sspf(v.w); }
          else if constexpr (ATR==2){
            float4 av = *(const float4*)(aux + (size_t)(m0+m)*lda + kc + kv);
            v.x*=sigf(av.x); v.y*=sigf(av.y); v.z*=sigf(av.z); v.w*=sigf(av.w);
          }
          else if constexpr (ATR==3){
            int kg = kc+kv;
            v.x = auxvec[kg+0]*sigf(v.x); v.y = auxvec[kg+1]*sigf(v.y);
            v.z = auxvec[kg+2]*sigf(v.z); v.w = auxvec[kg+3]*sigf(v.w);
          }
        }
      }
      As[kv+0][m]=v.x; As[kv+1][m]=v.y; As[kv+2][m]=v.z; As[kv+3][m]=v.w;
    }
    // ---- stage B chunk [32 x NN] ----
    if constexpr (!TRB){
      #pragma unroll
      for (int j=0;j<(BK*NN)/1024;j++){
        int p = t + j*256;
        int k = p / (NN/4);
        int nv = (p % (NN/4)) << 2;
        float4 v = make_float4(0.f,0.f,0.f,0.f);
        if (kc + k < Kreal) v = *(const float4*)(B + (size_t)(kc+k)*NN + nv);
        *(float4*)&Bs[k][nv] = v;
      }
    } else {
      #pragma unroll
      for (int j=0;j<(BK*NN)/1024;j++){
        int p = t + j*256;
        int n = p >> 3;
        int kv = (p & 7) << 2;
        float4 v = make_float4(0.f,0.f,0.f,0.f);
        if (n < Nreal) v = *(const float4*)(B + (size_t)n*KK + kc + kv);
        Bs[kv+0][n]=v.x; Bs[kv+1][n]=v.y; Bs[kv+2][n]=v.z; Bs[kv+3][n]=v.w;
      }
    }
    __syncthreads();
    #pragma unroll
    for (int k=0;k<BK;k++){
      float a[RT], b[8];
      #pragma unroll
      for (int i=0;i<RT;i+=4) *(float4*)&a[i] = *(const float4*)&As[k][ty*RT+i];
      *(float4*)&b[0] = *(const float4*)&Bs[k][tx*8];
      *(float4*)&b[4] = *(const float4*)&Bs[k][tx*8+4];
      #pragma unroll
      for (int i=0;i<RT;i++)
        #pragma unroll
        for (int j=0;j<8;j++)
          acc[i][j] = fmaf(a[i], b[j], acc[i][j]);
    }
    __syncthreads();
  }
  // ---- epilogue ----
  #pragma unroll
  for (int i=0;i<RT;i++){
    int r = m0 + ty*RT + i;
    if (r < M){
      float vo[8];
      #pragma unroll
      for (int j=0;j<8;j++){
        float v = acc[i][j];
        int c = tx*8 + j;
        if constexpr (BIAS) v += bias[c];
        if constexpr (OTR==1) v = sspf(v);
        else if constexpr (OTR==2) v *= sigf(oaux[(size_t)r*NN + c]);
        if constexpr (RES) v += res[(size_t)r*NN + c];
        vo[j] = v;
      }
      *(float4*)(out + (size_t)r*NN + tx*8)     = make_float4(vo[0],vo[1],vo[2],vo[3]);
      *(float4*)(out + (size_t)r*NN + tx*8 + 4) = make_float4(vo[4],vo[5],vo[6],vo[7]);
    }
  }
}

// dw[r] (+)= sum_g (dt1@W1^T)[r,g] * d(ea)/dw, ea recomputed from w
__global__ __launch_bounds__(256) void gemm_dw_k(
    const float* __restrict__ A /*dt1 [M,128]*/, const float* __restrict__ W1 /*[50,128]*/,
    const float* __restrict__ wv, float* __restrict__ dw, int M, int accum)
{
  constexpr int KK=128, TM=128, BK=32, TX=8, RT=4;
  __shared__ float As[BK][TM+4];
  __shared__ float Bs[BK][68];
  const int t = threadIdx.x;
  const int tx = t % TX, ty = t / TX;
  const int m0 = blockIdx.x * TM;
  float acc[RT][8];
  #pragma unroll
  for (int i=0;i<RT;i++)
    #pragma unroll
    for (int j=0;j<8;j++) acc[i][j]=0.f;

  for (int kc=0; kc<KK; kc+=BK){
    #pragma unroll
    for (int j=0;j<4;j++){
      int p = t + j*256;
      int m = p >> 3;
      int kv = (p & 7) << 2;
      float4 v = make_float4(0.f,0.f,0.f,0.f);
      if (m0+m < M) v = *(const float4*)(A + (size_t)(m0+m)*128 + kc + kv);
      As[kv+0][m]=v.x; As[kv+1][m]=v.y; As[kv+2][m]=v.z; As[kv+3][m]=v.w;
    }
    #pragma unroll
    for (int j=0;j<2;j++){
      int p = t + j*256;
      int n = p >> 3;
      int kv = (p & 7) << 2;
      float4 v = make_float4(0.f,0.f,0.f,0.f);
      if (n < 50) v = *(const float4*)(W1 + (size_t)n*128 + kc + kv);
      Bs[kv+0][n]=v.x; Bs[kv+1][n]=v.y; Bs[kv+2][n]=v.z; Bs[kv+3][n]=v.w;
    }
    __syncthreads();
    #pragma unroll
    for (int k=0;k<BK;k++){
      float a[RT], b[8];
      *(float4*)&a[0] = *(const float4*)&As[k][ty*RT];
      *(float4*)&b[0] = *(const float4*)&Bs[k][tx*8];
      *(float4*)&b[4] = *(const float4*)&Bs[k][tx*8+4];
      #pragma unroll
      for (int i=0;i<RT;i++)
        #pragma unroll
        for (int j=0;j<8;j++)
          acc[i][j] = fmaf(a[i], b[j], acc[i][j]);
    }
    __syncthreads();
  }
  #pragma unroll
  for (int i=0;i<RT;i++){
    int r = m0 + ty*RT + i;
    float s = 0.f;
    if (r < M){
      float w = wv[r];
      #pragma unroll
      for (int j=0;j<8;j++){
        int c = tx*8+j;
        if (c < 50){
          float d = w - (float)c*DMU;
          s += acc[i][j] * (2.f*GC*d) * expf(GC*d*d);
        }
      }
    }
    s += __shfl_xor(s, 1);
    s += __shfl_xor(s, 2);
    s += __shfl_xor(s, 4);
    if (tx==0 && r<M) dw[r] = accum ? (dw[r]+s) : s;
  }
}

// ---------------------------------------------------------------------------
// edge geometry: w and cosine cutoff only
// ---------------------------------------------------------------------------
__global__ void edge_geom_k(const float* __restrict__ pos, const int* __restrict__ ei,
                            const float* __restrict__ off, const float* __restrict__ cell,
                            float* __restrict__ wv, float* __restrict__ Cv, int E)
{
  int e = blockIdx.x*256 + threadIdx.x;
  if (e>=E) return;
  int r = ei[e], c = ei[E+e];
  float o0=off[3*e], o1=off[3*e+1], o2=off[3*e+2];
  float d0 = o0*cell[0] + o1*cell[3] + o2*cell[6];
  float d1 = o0*cell[1] + o1*cell[4] + o2*cell[7];
  float d2 = o0*cell[2] + o1*cell[5] + o2*cell[8];
  float v0 = pos[3*r+0]-pos[3*c+0]+d0;
  float v1 = pos[3*r+1]-pos[3*c+1]+d1;
  float v2 = pos[3*r+2]-pos[3*c+2]+d2;
  float w = sqrtf(v0*v0+v1*v1+v2*v2);
  wv[e]=w;
  Cv[e]=0.5f*cosf(w*(PI_F/4.0f)) + 0.5f;
}

__global__ void embed_k(const float* __restrict__ emb, const int* __restrict__ z,
                        float* __restrict__ h, int total){
  int i = blockIdx.x*256 + threadIdx.x;
  if (i < total){ int n=i>>7, j=i&127; h[i] = emb[(size_t)z[n]*128 + j]; }
}

// forward scatter: agg[col] += xh[row]*Wfc*C  (one wave per edge)
__global__ __launch_bounds__(256) void scatter_fw_k(
    const float* __restrict__ xh, const float* __restrict__ Wfc,
    const float* __restrict__ Cv, const int* __restrict__ ei, int E0, int E,
    float* __restrict__ agg, int len)
{
  int w = threadIdx.x>>6, lane = threadIdx.x&63;
  int j = blockIdx.x*4 + w;
  if (j>=len) return;
  int e = E0 + j;
  int r = ei[e], c = ei[E+e];
  float ce = Cv[e];
  float2 wf = *(const float2*)(Wfc + (size_t)j*128 + lane*2);
  float2 xv = *(const float2*)(xh + (size_t)r*128 + lane*2);
  atomicAdd(agg + (size_t)c*128 + lane*2,     xv.x*ce*wf.x);
  atomicAdd(agg + (size_t)c*128 + lane*2 + 1, xv.y*ce*wf.y);
}

// backward per-edge: dxh[row] += dagg[col]*Wfc*C (atomic); dC[e] (+)= dot(dagg*xh, Wfc);
// Wfc := dagg[col]*xh[row]*C (in place, becomes dWf)
__global__ __launch_bounds__(256) void edge_bwd_k(
    const float* __restrict__ dagg, const float* __restrict__ xh,
    float* __restrict__ Wfc, const float* __restrict__ Cv,
    const int* __restrict__ ei, int E0, int E,
    float* __restrict__ dxh, float* __restrict__ dC, int len, int accum)
{
  int w = threadIdx.x>>6, lane = threadIdx.x&63;
  int j = blockIdx.x*4 + w;
  if (j>=len) return;
  int e = E0 + j;
  int r = ei[e], c = ei[E+e];
  float ce = Cv[e];
  float2 da = *(const float2*)(dagg + (size_t)c*128 + lane*2);
  float2 xv = *(const float2*)(xh + (size_t)r*128 + lane*2);
  float2 wf = *(const float2*)(Wfc + (size_t)j*128 + lane*2);
  atomicAdd(dxh + (size_t)r*128 + lane*2,     da.x*ce*wf.x);
  atomicAdd(dxh + (size_t)r*128 + lane*2 + 1, da.y*ce*wf.y);
  float dx = da.x*xv.x, dy = da.y*xv.y;
  float part = dx*wf.x + dy*wf.y;
  #pragma unroll
  for (int m=1;m<64;m<<=1) part += __shfl_xor(part, m);
  if (lane==0) dC[e] = accum ? (dC[e]+part) : part;
  *(float2*)(Wfc + (size_t)j*128 + lane*2) = make_float2(dx*ce, dy*ce);
}

// readout energy
__global__ void head_k(const float* __restrict__ u, const float* __restrict__ o2,
                       const float* __restrict__ o2b, float* __restrict__ out0, int N){
  int n = blockIdx.x*256 + threadIdx.x;
  float s = 0.f;
  if (n < N){
    #pragma unroll
    for (int k=0;k<64;k+=4){
      float4 uv = *(const float4*)(u + (size_t)n*64 + k);
      float4 ov = *(const float4*)(o2 + k);
      s += sspf(uv.x)*ov.x + sspf(uv.y)*ov.y + sspf(uv.z)*ov.z + sspf(uv.w)*ov.w;
    }
  }
  #pragma unroll
  for (int m=1;m<64;m<<=1) s += __shfl_xor(s, m);
  __shared__ float red[4];
  int lane = threadIdx.x&63, w = threadIdx.x>>6;
  if (lane==0) red[w]=s;
  __syncthreads();
  if (threadIdx.x==0){
    float tot = red[0]+red[1]+red[2]+red[3];
    if (blockIdx.x==0) tot += (float)N * o2b[0];
    atomicAdd(out0, tot);
  }
}

// forces: recompute vec, dvec = vec*(dw + dC*dCdw)/w, atomic scatter to f
__global__ void force_k(const float* __restrict__ dw, const float* __restrict__ dC,
                        const float* __restrict__ wv,
                        const float* __restrict__ pos, const int* __restrict__ ei,
                        const float* __restrict__ off, const float* __restrict__ cell,
                        float* __restrict__ f, int E)
{
  int e = blockIdx.x*256 + threadIdx.x;
  if (e>=E) return;
  int r = ei[e], c = ei[E+e];
  float o0=off[3*e], o1=off[3*e+1], o2=off[3*e+2];
  float d0 = o0*cell[0] + o1*cell[3] + o2*cell[6];
  float d1 = o0*cell[1] + o1*cell[4] + o2*cell[7];
  float d2 = o0*cell[2] + o1*cell[5] + o2*cell[8];
  float v0 = pos[3*r+0]-pos[3*c+0]+d0;
  float v1 = pos[3*r+1]-pos[3*c+1]+d1;
  float v2 = pos[3*r+2]-pos[3*c+2]+d2;
  float w = wv[e];
  float dwt = dw[e] + dC[e] * (-0.5f*(PI_F/4.0f)) * sinf(w*(PI_F/4.0f));
  float s = dwt / w;
  // force = -dE/dpos: dE/dpos[row] += dvec, dE/dpos[col] -= dvec
  atomicAdd(&f[3*r+0], -v0*s); atomicAdd(&f[3*r+1], -v1*s); atomicAdd(&f[3*r+2], -v2*s);
  atomicAdd(&f[3*c+0],  v0*s); atomicAdd(&f[3*c+1],  v1*s); atomicAdd(&f[3*c+2],  v2*s);
}

// ---------------------------------------------------------------------------
extern "C" void kernel_launch(void* const* d_in, const int* in_sizes, int n_in,
                              void* d_out, int out_size, void* d_ws, size_t ws_size,
                              hipStream_t stream)
{
  const int N = in_sizes[0];
  const int E = in_sizes[2]/2;
  const int L = 6;
  const int* z        = (const int*)d_in[0];
  const float* pos    = (const float*)d_in[1];
  const int* ei       = (const int*)d_in[2];
  const float* offset = (const float*)d_in[3];
  const float* cell   = (const float*)d_in[4];
  const float* emb    = (const float*)d_in[5];
  const float* mlp_w1 = (const float*)d_in[6];
  const float* mlp_b1 = (const float*)d_in[7];
  const float* mlp_w2 = (const float*)d_in[8];
  const float* mlp_b2 = (const float*)d_in[9];
  const float* conv_w1= (const float*)d_in[10];
  const float* conv_w2= (const float*)d_in[11];
  const float* conv_b2= (const float*)d_in[12];
  const float* lin_w  = (const float*)d_in[13];
  const float* lin_b  = (const float*)d_in[14];
  const float* out1_w = (const float*)d_in[15];
  const float* out1_b = (const float*)d_in[16];
  const float* out2_w = (const float*)d_in[17];
  const float* out2_b = (const float*)d_in[18];
  float* out = (float*)d_out;

  char* wp = (char*)d_ws;
  auto alloc = [&](size_t bytes)->char*{ char* p = wp; wp += (bytes + 255) & ~(size_t)255; return p; };
  float* wbuf = (float*)alloc((size_t)E*4);
  float* Cbuf = (float*)alloc((size_t)E*4);
  float* dCb  = (float*)alloc((size_t)E*4);
  float* dwb  = (float*)alloc((size_t)E*4);
  float* xh   = (float*)alloc((size_t)L*N*128*4);
  float* mbuf = (float*)alloc((size_t)L*N*128*4);
  float* ubuf = (float*)alloc((size_t)N*64*4);
  float* hbuf = (float*)alloc((size_t)N*128*4);
  float* Gbuf = (float*)alloc((size_t)N*128*4);
  float* bufA = (float*)alloc((size_t)N*128*4);
  float* bufB = (float*)alloc((size_t)N*128*4);
  float* bufC = (float*)alloc((size_t)N*128*4);   // dxh
  float* aggb = (float*)alloc((size_t)N*128*4);

  // adaptive chunk size for the two [CH,128] edge buffers
  size_t used = (size_t)(wp - (char*)d_ws);
  long remain = (long)ws_size - (long)used - 4096;
  long CHl = remain / (2*128*4);
  long Epad = ((long)E + 127)/128*128;
  if (CHl > 65536) CHl = 65536;
  if (CHl > Epad) CHl = Epad;
  int CH = (int)((CHl/128)*128);
  if (CH < 4096) CH = 4096;
  float* s1c = (float*)alloc((size_t)CH*128*4);
  float* Wfc = (float*)alloc((size_t)CH*128*4);
  const int nch = (E + CH - 1)/CH;

  const int egrid = (E+255)/256;
  const int ng = (N+127)/128;

  hipMemsetAsync(d_out, 0, (size_t)out_size*4, stream);
  edge_geom_k<<<egrid,256,0,stream>>>(pos, ei, offset, cell, wbuf, Cbuf, E);
  embed_k<<<(N*128+255)/256,256,0,stream>>>(emb, z, hbuf, N*128);

  // ---------------- forward ----------------
  for (int i=0;i<L;i++){
    const float* w1i = mlp_w1 + (size_t)i*50*128;
    const float* b1i = mlp_b1 + (size_t)i*128;
    const float* w2i = mlp_w2 + (size_t)i*128*128;
    const float* b2i = mlp_b2 + (size_t)i*128;
    const float* cw1i= conv_w1+ (size_t)i*128*128;
    const float* cw2i= conv_w2+ (size_t)i*128*128;
    const float* cb2i= conv_b2+ (size_t)i*128;
    const float* lwi = lin_w  + (size_t)i*128*128;
    const float* lbi = lin_b  + (size_t)i*128;
    float* xhi = xh   + (size_t)i*N*128;
    float* mi  = mbuf + (size_t)i*N*128;

    gemm_k<128,128,false,0,false,0,false><<<ng,256,0,stream>>>(
      hbuf, 128, nullptr, nullptr, cw1i, 128, 128, nullptr, nullptr, nullptr, xhi, N);
    hipMemsetAsync(aggb, 0, (size_t)N*128*4, stream);
    for (int c=0;c<nch;c++){
      int st = c*CH; int len = E-st; if (len > CH) len = CH;
      int g = (len+127)/128;
      gemm_k<64,128,false,4,true,1,false><<<g,256,0,stream>>>(
        wbuf+st, 64, wbuf+st, nullptr, w1i, 50, 128, b1i, nullptr, nullptr, s1c, len);
      gemm_k<128,128,false,0,true,0,false><<<g,256,0,stream>>>(
        s1c, 128, nullptr, nullptr, w2i, 128, 128, b2i, nullptr, nullptr, Wfc, len);
      scatter_fw_k<<<(len+3)/4,256,0,stream>>>(xhi, Wfc, Cbuf, ei, st, E, aggb, len);
    }
    gemm_k<128,128,false,0,true,0,false><<<ng,256,0,stream>>>(
      aggb, 128, nullptr, nullptr, cw2i, 128, 128, cb2i, nullptr, nullptr, mi, N);
    gemm_k<128,128,false,1,true,0,true><<<ng,256,0,stream>>>(
      mi, 128, nullptr, nullptr, lwi, 128, 128, lbi, hbuf, nullptr, hbuf, N);
  }

  // head: u = h@o1+b ; E = sum ssp(u)@o2 + N*o2b ; G = (o2*sig(u))@o1^T
  gemm_k<128,64,false,0,true,0,false><<<ng,256,0,stream>>>(
    hbuf, 128, nullptr, nullptr, out1_w, 128, 64, out1_b, nullptr, nullptr, ubuf, N);
  head_k<<<(N+255)/256,256,0,stream>>>(ubuf, out2_w, out2_b, out, N);
  gemm_k<64,128,true,3,false,0,false><<<ng,256,0,stream>>>(
    ubuf, 64, nullptr, out2_w, out1_w, 64, 128, nullptr, nullptr, nullptr, Gbuf, N);

  // ---------------- backward ----------------
  for (int i=L-1;i>=0;i--){
    const float* w1i = mlp_w1 + (size_t)i*50*128;
    const float* b1i = mlp_b1 + (size_t)i*128;
    const float* w2i = mlp_w2 + (size_t)i*128*128;
    const float* b2i = mlp_b2 + (size_t)i*128;
    const float* cw1i= conv_w1+ (size_t)i*128*128;
    const float* cw2i= conv_w2+ (size_t)i*128*128;
    const float* lwi = lin_w  + (size_t)i*128*128;
    float* xhi = xh   + (size_t)i*N*128;
    float* mi  = mbuf + (size_t)i*N*128;
    int first = (i==L-1) ? 0 : 1;

    // dsm = G @ lw^T ; dagg = (dsm*sig(m)) @ cw2^T
    gemm_k<128,128,true,0,false,0,false><<<ng,256,0,stream>>>(
      Gbuf, 128, nullptr, nullptr, lwi, 128, 128, nullptr, nullptr, nullptr, bufA, N);
    gemm_k<128,128,true,2,false,0,false><<<ng,256,0,stream>>>(
      bufA, 128, mi, nullptr, cw2i, 128, 128, nullptr, nullptr, nullptr, bufB, N);
    hipMemsetAsync(bufC, 0, (size_t)N*128*4, stream);
    for (int c=0;c<nch;c++){
      int st = c*CH; int len = E-st; if (len > CH) len = CH;
      int g = (len+127)/128;
      // recompute s1, Wf for this chunk
      gemm_k<64,128,false,4,true,1,false><<<g,256,0,stream>>>(
        wbuf+st, 64, wbuf+st, nullptr, w1i, 50, 128, b1i, nullptr, nullptr, s1c, len);
      gemm_k<128,128,false,0,true,0,false><<<g,256,0,stream>>>(
        s1c, 128, nullptr, nullptr, w2i, 128, 128, b2i, nullptr, nullptr, Wfc, len);
      // dxh scatter + dC + dWf (in place)
      edge_bwd_k<<<(len+3)/4,256,0,stream>>>(bufB, xhi, Wfc, Cbuf, ei, st, E, bufC, dCb, len, first);
      // dt1 = (dWf @ w2^T)*sig(s1), in place into s1c
      gemm_k<128,128,true,0,false,2,false><<<g,256,0,stream>>>(
        Wfc, 128, nullptr, nullptr, w2i, 128, 128, nullptr, nullptr, s1c, s1c, len);
      // dw (+)= fused smearing chain
      gemm_dw_k<<<g,256,0,stream>>>(s1c, w1i, wbuf+st, dwb+st, len, first);
    }
    // G += dxh @ cw1^T
    gemm_k<128,128,true,0,false,0,true><<<ng,256,0,stream>>>(
      bufC, 128, nullptr, nullptr, cw1i, 128, 128, nullptr, Gbuf, nullptr, Gbuf, N);
  }

  force_k<<<egrid,256,0,stream>>>(dwb, dCb, wbuf, pos, ei, offset, cell, out+1, E);
}

// Round 4
// 7950.596 us; speedup vs baseline: 1.3916x; 1.3916x over previous
//
#include <hip/hip_runtime.h>
#include <math.h>

#define LN2F 0.69314718055994530942f
#define PI_F 3.14159265358979323846f
constexpr float DMU = 4.0f/49.0f;          // gaussian spacing, linspace(0,4,50)
constexpr float GC  = -0.5f/(DMU*DMU);     // smearing coeff

typedef __bf16 bf16x8 __attribute__((ext_vector_type(8)));
typedef __bf16 bf16x2 __attribute__((ext_vector_type(2)));
typedef float  f32x4  __attribute__((ext_vector_type(4)));

__device__ __forceinline__ float sspf(float x){
  return fmaxf(x, 0.f) + log1pf(expf(-fabsf(x))) - LN2F;
}
__device__ __forceinline__ float sigf(float x){ return 1.f/(1.f+expf(-x)); }

// ---------------------------------------------------------------------------
// fp32 GEMM (node-level, small M=N=10000): out[M,NN] = epi( A'[M,KK] @ B[KK,NN] )
// ---------------------------------------------------------------------------
template<int KK,int NN,bool TRB,int ATR,bool BIAS,int OTR,bool RES>
__global__ __launch_bounds__(256) void gemm_k(
    const float* __restrict__ A, int lda,
    const float* __restrict__ aux, const float* __restrict__ auxvec,
    const float* __restrict__ B, int Kreal, int Nreal,
    const float* __restrict__ bias, const float* __restrict__ res,
    const float* __restrict__ oaux, float* __restrict__ out, int M)
{
  constexpr int TM = 128, BK = 32;
  constexpr int TX = (NN==128)?16:8;
  constexpr int RT = (NN==128)?8:4;
  __shared__ float As[BK][TM+4];
  __shared__ float Bs[BK][NN+4];
  const int t = threadIdx.x;
  const int tx = t % TX, ty = t / TX;
  const int m0 = blockIdx.x * TM;
  float acc[RT][8];
  #pragma unroll
  for (int i=0;i<RT;i++)
    #pragma unroll
    for (int j=0;j<8;j++) acc[i][j]=0.f;

  for (int kc=0; kc<KK; kc+=BK){
    #pragma unroll
    for (int j=0;j<4;j++){
      int p = t + j*256;
      int m = p >> 3;
      int kv = (p & 7) << 2;
      float4 v = make_float4(0.f,0.f,0.f,0.f);
      if (m0+m < M){
        v = *(const float4*)(A + (size_t)(m0+m)*lda + kc + kv);
        if constexpr (ATR==1){ v.x=sspf(v.x); v.y=sspf(v.y); v.z=sspf(v.z); v.w=sspf(v.w); }
        else if constexpr (ATR==2){
          float4 av = *(const float4*)(aux + (size_t)(m0+m)*lda + kc + kv);
          v.x*=sigf(av.x); v.y*=sigf(av.y); v.z*=sigf(av.z); v.w*=sigf(av.w);
        }
        else if constexpr (ATR==3){
          int kg = kc+kv;
          v.x = auxvec[kg+0]*sigf(v.x); v.y = auxvec[kg+1]*sigf(v.y);
          v.z = auxvec[kg+2]*sigf(v.z); v.w = auxvec[kg+3]*sigf(v.w);
        }
      }
      As[kv+0][m]=v.x; As[kv+1][m]=v.y; As[kv+2][m]=v.z; As[kv+3][m]=v.w;
    }
    if constexpr (!TRB){
      #pragma unroll
      for (int j=0;j<(BK*NN)/1024;j++){
        int p = t + j*256;
        int k = p / (NN/4);
        int nv = (p % (NN/4)) << 2;
        float4 v = make_float4(0.f,0.f,0.f,0.f);
        if (kc + k < Kreal) v = *(const float4*)(B + (size_t)(kc+k)*NN + nv);
        *(float4*)&Bs[k][nv] = v;
      }
    } else {
      #pragma unroll
      for (int j=0;j<(BK*NN)/1024;j++){
        int p = t + j*256;
        int n = p >> 3;
        int kv = (p & 7) << 2;
        float4 v = make_float4(0.f,0.f,0.f,0.f);
        if (n < Nreal) v = *(const float4*)(B + (size_t)n*KK + kc + kv);
        Bs[kv+0][n]=v.x; Bs[kv+1][n]=v.y; Bs[kv+2][n]=v.z; Bs[kv+3][n]=v.w;
      }
    }
    __syncthreads();
    #pragma unroll
    for (int k=0;k<BK;k++){
      float a[RT], b[8];
      #pragma unroll
      for (int i=0;i<RT;i+=4) *(float4*)&a[i] = *(const float4*)&As[k][ty*RT+i];
      *(float4*)&b[0] = *(const float4*)&Bs[k][tx*8];
      *(float4*)&b[4] = *(const float4*)&Bs[k][tx*8+4];
      #pragma unroll
      for (int i=0;i<RT;i++)
        #pragma unroll
        for (int j=0;j<8;j++)
          acc[i][j] = fmaf(a[i], b[j], acc[i][j]);
    }
    __syncthreads();
  }
  #pragma unroll
  for (int i=0;i<RT;i++){
    int r = m0 + ty*RT + i;
    if (r < M){
      float vo[8];
      #pragma unroll
      for (int j=0;j<8;j++){
        float v = acc[i][j];
        int c = tx*8 + j;
        if constexpr (BIAS) v += bias[c];
        if constexpr (OTR==1) v = sspf(v);
        else if constexpr (OTR==2) v *= sigf(oaux[(size_t)r*NN + c]);
        if constexpr (RES) v += res[(size_t)r*NN + c];
        vo[j] = v;
      }
      *(float4*)(out + (size_t)r*NN + tx*8)     = make_float4(vo[0],vo[1],vo[2],vo[3]);
      *(float4*)(out + (size_t)r*NN + tx*8 + 4) = make_float4(vo[4],vo[5],vo[6],vo[7]);
    }
  }
}

// ---------------------------------------------------------------------------
// bf16 MFMA GEMM (edge-level): out[M,128] = epi( A[M,KK] @ B[KK,128] ), bf16 out.
// Bt is B^T laid out [128][KK] bf16, k-contiguous.
// ATR: 0 = A bf16 [M,KK]; 4 = gaussian smearing computed from wv[M]
// OTR: 0=none, 1=ssp, 2= *oaux[r,c] (bf16), 3= out=ssp(t), out2=sigmoid(t)
// Tile: 64 rows x 128 cols, 4 waves, wave = 1 m-tile x 8 n-tiles of 16x16x32.
// ---------------------------------------------------------------------------
template<int KK,int ATR,bool BIAS,int OTR>
__global__ __launch_bounds__(256) void mgemm_k(
    const __bf16* __restrict__ A, const float* __restrict__ wv,
    const __bf16* __restrict__ Bt, const float* __restrict__ bias,
    const __bf16* __restrict__ oaux, __bf16* __restrict__ out,
    __bf16* __restrict__ out2, int M)
{
  constexpr int KP = KK + 8;           // row pad keeps 16B align, breaks bank conflicts
  __shared__ __align__(16) __bf16 As[64][KP];
  __shared__ __align__(16) __bf16 Bs[128][KP];
  const int t = threadIdx.x;
  const int m0 = blockIdx.x * 64;
  constexpr int RPT = KK/8;            // 8-elt groups per row

  // stage A [64 x KK]
  #pragma unroll
  for (int it=0; it<(64*RPT)/256; ++it){
    int p = t + it*256;
    int row = p / RPT;
    int ko = (p % RPT)*8;
    if constexpr (ATR==4){
      float w = (m0+row < M) ? wv[m0+row] : 0.f;
      bf16x8 tmp;
      #pragma unroll
      for (int j=0;j<8;j++){
        int k = ko+j;
        float d = w - (float)k*DMU;
        float val = (k<50) ? __expf(GC*d*d) : 0.f;
        tmp[j] = (__bf16)val;
      }
      *(bf16x8*)&As[row][ko] = tmp;
    } else {
      uint4 v = make_uint4(0,0,0,0);
      if (m0+row < M) v = *(const uint4*)(A + (size_t)(m0+row)*KK + ko);
      *(uint4*)&As[row][ko] = v;
    }
  }
  // stage Bt [128 x KK]
  #pragma unroll
  for (int it=0; it<(128*RPT)/256; ++it){
    int p = t + it*256;
    int row = p / RPT;
    int ko = (p % RPT)*8;
    *(uint4*)&Bs[row][ko] = *(const uint4*)(Bt + (size_t)row*KK + ko);
  }
  __syncthreads();

  const int wid = t >> 6, lane = t & 63;
  const int quad = lane >> 4, ln = lane & 15;
  f32x4 acc[8];
  #pragma unroll
  for (int nt=0;nt<8;nt++) acc[nt] = (f32x4){0.f,0.f,0.f,0.f};

  #pragma unroll
  for (int ks=0; ks<KK; ks+=32){
    bf16x8 a = *(const bf16x8*)&As[wid*16 + ln][ks + quad*8];
    #pragma unroll
    for (int nt=0; nt<8; nt++){
      bf16x8 b = *(const bf16x8*)&Bs[nt*16 + ln][ks + quad*8];
      acc[nt] = __builtin_amdgcn_mfma_f32_16x16x32_bf16(a, b, acc[nt], 0, 0, 0);
    }
  }

  // epilogue: row = m0 + wid*16 + quad*4 + reg, col = nt*16 + ln
  #pragma unroll
  for (int reg=0; reg<4; reg++){
    int r = m0 + wid*16 + quad*4 + reg;
    if (r < M){
      #pragma unroll
      for (int nt=0; nt<8; nt++){
        int c = nt*16 + ln;
        float v = acc[nt][reg];
        if constexpr (BIAS) v += bias[c];
        if constexpr (OTR==1) v = sspf(v);
        else if constexpr (OTR==2) v *= (float)oaux[(size_t)r*128 + c];
        else if constexpr (OTR==3){
          out2[(size_t)r*128 + c] = (__bf16)sigf(v);
          v = sspf(v);
        }
        out[(size_t)r*128 + c] = (__bf16)v;
      }
    }
  }
}

// ---------------------------------------------------------------------------
// dw MFMA GEMM: dea = dt1[M,128] @ W1^T (Bt=W1c [64][128]); epilogue contracts
// dea over gaussian-derivative to dw[r]. Tile 128x64, wave = 2 m-tiles x 4 n-tiles.
// ---------------------------------------------------------------------------
__global__ __launch_bounds__(256) void gemm_dw_m(
    const __bf16* __restrict__ A, const __bf16* __restrict__ Bt,
    const float* __restrict__ wv, float* __restrict__ dw, int M, int accum)
{
  __shared__ __align__(16) __bf16 As[128][136];
  __shared__ __align__(16) __bf16 Bs[64][136];
  const int t = threadIdx.x;
  const int m0 = blockIdx.x * 128;

  #pragma unroll
  for (int it=0; it<8; ++it){
    int p = t + it*256;
    int row = p >> 4;
    int ko = (p & 15)*8;
    uint4 v = make_uint4(0,0,0,0);
    if (m0+row < M) v = *(const uint4*)(A + (size_t)(m0+row)*128 + ko);
    *(uint4*)&As[row][ko] = v;
  }
  #pragma unroll
  for (int it=0; it<4; ++it){
    int p = t + it*256;
    int row = p >> 4;
    int ko = (p & 15)*8;
    *(uint4*)&Bs[row][ko] = *(const uint4*)(Bt + (size_t)row*128 + ko);
  }
  __syncthreads();

  const int wid = t >> 6, lane = t & 63;
  const int quad = lane >> 4, ln = lane & 15;
  f32x4 acc[2][4];
  #pragma unroll
  for (int mt=0;mt<2;mt++)
    #pragma unroll
    for (int nt=0;nt<4;nt++) acc[mt][nt] = (f32x4){0.f,0.f,0.f,0.f};

  #pragma unroll
  for (int ks=0; ks<128; ks+=32){
    bf16x8 a0 = *(const bf16x8*)&As[wid*32 + ln][ks + quad*8];
    bf16x8 a1 = *(const bf16x8*)&As[wid*32 + 16 + ln][ks + quad*8];
    #pragma unroll
    for (int nt=0; nt<4; nt++){
      bf16x8 b = *(const bf16x8*)&Bs[nt*16 + ln][ks + quad*8];
      acc[0][nt] = __builtin_amdgcn_mfma_f32_16x16x32_bf16(a0, b, acc[0][nt], 0, 0, 0);
      acc[1][nt] = __builtin_amdgcn_mfma_f32_16x16x32_bf16(a1, b, acc[1][nt], 0, 0, 0);
    }
  }

  #pragma unroll
  for (int mt=0; mt<2; mt++){
    #pragma unroll
    for (int reg=0; reg<4; reg++){
      int r = m0 + wid*32 + mt*16 + quad*4 + reg;
      float w = (r < M) ? wv[r] : 0.f;
      float s = 0.f;
      #pragma unroll
      for (int nt=0; nt<4; nt++){
        int c = nt*16 + ln;
        if (c < 50){
          float d = w - (float)c*DMU;
          s += acc[mt][nt][reg] * (2.f*GC*d) * __expf(GC*d*d);
        }
      }
      s += __shfl_xor(s, 1);
      s += __shfl_xor(s, 2);
      s += __shfl_xor(s, 4);
      s += __shfl_xor(s, 8);
      if (ln==0 && r < M) dw[r] = accum ? (dw[r]+s) : s;
    }
  }
}

// ---------------------------------------------------------------------------
// one-time bf16 weight conversion into the 4 layouts the MFMA GEMMs want
// ---------------------------------------------------------------------------
__global__ void convw_k(const float* __restrict__ w1, const float* __restrict__ w2,
                        __bf16* __restrict__ W1t, __bf16* __restrict__ W2t,
                        __bf16* __restrict__ W2c, __bf16* __restrict__ W1c, int total)
{
  int idx = blockIdx.x*256 + threadIdx.x;
  if (idx >= total) return;
  int l = idx / 49152;
  int r = idx % 49152;
  if (r < 8192){                       // W1t[n][k] = w1[k][n], k<50
    int n = r / 64, k = r % 64;
    float v = (k<50) ? w1[(size_t)l*6400 + k*128 + n] : 0.f;
    W1t[(size_t)l*8192 + r] = (__bf16)v;
  } else if (r < 24576){               // W2t[n][k] = w2[k][n]
    int r2 = r - 8192;
    int n = r2 / 128, k = r2 % 128;
    W2t[(size_t)l*16384 + r2] = (__bf16)w2[(size_t)l*16384 + k*128 + n];
  } else if (r < 40960){               // W2c = w2 (elementwise)
    int r2 = r - 24576;
    W2c[(size_t)l*16384 + r2] = (__bf16)w2[(size_t)l*16384 + r2];
  } else {                             // W1c[n][k] = w1[n][k], n<50
    int r2 = r - 40960;
    int n = r2 / 128, k = r2 % 128;
    float v = (n<50) ? w1[(size_t)l*6400 + n*128 + k] : 0.f;
    W1c[(size_t)l*8192 + r2] = (__bf16)v;
  }
}

// ---------------------------------------------------------------------------
__global__ void edge_geom_k(const float* __restrict__ pos, const int* __restrict__ ei,
                            const float* __restrict__ off, const float* __restrict__ cell,
                            float* __restrict__ wv, float* __restrict__ Cv, int E)
{
  int e = blockIdx.x*256 + threadIdx.x;
  if (e>=E) return;
  int r = ei[e], c = ei[E+e];
  float o0=off[3*e], o1=off[3*e+1], o2=off[3*e+2];
  float d0 = o0*cell[0] + o1*cell[3] + o2*cell[6];
  float d1 = o0*cell[1] + o1*cell[4] + o2*cell[7];
  float d2 = o0*cell[2] + o1*cell[5] + o2*cell[8];
  float v0 = pos[3*r+0]-pos[3*c+0]+d0;
  float v1 = pos[3*r+1]-pos[3*c+1]+d1;
  float v2 = pos[3*r+2]-pos[3*c+2]+d2;
  float w = sqrtf(v0*v0+v1*v1+v2*v2);
  wv[e]=w;
  Cv[e]=0.5f*cosf(w*(PI_F/4.0f)) + 0.5f;
}

__global__ void embed_k(const float* __restrict__ emb, const int* __restrict__ z,
                        float* __restrict__ h, int total){
  int i = blockIdx.x*256 + threadIdx.x;
  if (i < total){ int n=i>>7, j=i&127; h[i] = emb[(size_t)z[n]*128 + j]; }
}

// forward scatter: agg[col] += xh[row]*Wf*C  (one wave per edge, bf16 Wf)
__global__ __launch_bounds__(256) void scatter_fw_k(
    const float* __restrict__ xh, const __bf16* __restrict__ Wfc,
    const float* __restrict__ Cv, const int* __restrict__ ei, int E0, int E,
    float* __restrict__ agg, int len)
{
  int w = threadIdx.x>>6, lane = threadIdx.x&63;
  int j = blockIdx.x*4 + w;
  if (j>=len) return;
  int e = E0 + j;
  int r = ei[e], c = ei[E+e];
  float ce = Cv[e];
  bf16x2 wf = *(const bf16x2*)(Wfc + (size_t)j*128 + lane*2);
  float2 xv = *(const float2*)(xh + (size_t)r*128 + lane*2);
  atomicAdd(agg + (size_t)c*128 + lane*2,     xv.x*ce*(float)wf[0]);
  atomicAdd(agg + (size_t)c*128 + lane*2 + 1, xv.y*ce*(float)wf[1]);
}

// backward per-edge: dxh[row] += dagg[col]*Wf*C; dC[e] (+)= dot(dagg*xh, Wf);
// Wfc := dagg[col]*xh[row]*C (in place -> dWf, bf16)
__global__ __launch_bounds__(256) void edge_bwd_k(
    const float* __restrict__ dagg, const float* __restrict__ xh,
    __bf16* __restrict__ Wfc, const float* __restrict__ Cv,
    const int* __restrict__ ei, int E0, int E,
    float* __restrict__ dxh, float* __restrict__ dC, int len, int accum)
{
  int w = threadIdx.x>>6, lane = threadIdx.x&63;
  int j = blockIdx.x*4 + w;
  if (j>=len) return;
  int e = E0 + j;
  int r = ei[e], c = ei[E+e];
  float ce = Cv[e];
  float2 da = *(const float2*)(dagg + (size_t)c*128 + lane*2);
  float2 xv = *(const float2*)(xh + (size_t)r*128 + lane*2);
  bf16x2 wf = *(const bf16x2*)(Wfc + (size_t)j*128 + lane*2);
  atomicAdd(dxh + (size_t)r*128 + lane*2,     da.x*ce*(float)wf[0]);
  atomicAdd(dxh + (size_t)r*128 + lane*2 + 1, da.y*ce*(float)wf[1]);
  float dx = da.x*xv.x, dy = da.y*xv.y;
  float part = dx*(float)wf[0] + dy*(float)wf[1];
  #pragma unroll
  for (int m=1;m<64;m<<=1) part += __shfl_xor(part, m);
  if (lane==0) dC[e] = accum ? (dC[e]+part) : part;
  bf16x2 o; o[0] = (__bf16)(dx*ce); o[1] = (__bf16)(dy*ce);
  *(bf16x2*)(Wfc + (size_t)j*128 + lane*2) = o;
}

// readout energy
__global__ void head_k(const float* __restrict__ u, const float* __restrict__ o2,
                       const float* __restrict__ o2b, float* __restrict__ out0, int N){
  int n = blockIdx.x*256 + threadIdx.x;
  float s = 0.f;
  if (n < N){
    #pragma unroll
    for (int k=0;k<64;k+=4){
      float4 uv = *(const float4*)(u + (size_t)n*64 + k);
      float4 ov = *(const float4*)(o2 + k);
      s += sspf(uv.x)*ov.x + sspf(uv.y)*ov.y + sspf(uv.z)*ov.z + sspf(uv.w)*ov.w;
    }
  }
  #pragma unroll
  for (int m=1;m<64;m<<=1) s += __shfl_xor(s, m);
  __shared__ float red[4];
  int lane = threadIdx.x&63, w = threadIdx.x>>6;
  if (lane==0) red[w]=s;
  __syncthreads();
  if (threadIdx.x==0){
    float tot = red[0]+red[1]+red[2]+red[3];
    if (blockIdx.x==0) tot += (float)N * o2b[0];
    atomicAdd(out0, tot);
  }
}

// forces: recompute vec, dvec = vec*(dw + dC*dCdw)/w, atomic scatter to f
__global__ void force_k(const float* __restrict__ dw, const float* __restrict__ dC,
                        const float* __restrict__ wv,
                        const float* __restrict__ pos, const int* __restrict__ ei,
                        const float* __restrict__ off, const float* __restrict__ cell,
                        float* __restrict__ f, int E)
{
  int e = blockIdx.x*256 + threadIdx.x;
  if (e>=E) return;
  int r = ei[e], c = ei[E+e];
  float o0=off[3*e], o1=off[3*e+1], o2=off[3*e+2];
  float d0 = o0*cell[0] + o1*cell[3] + o2*cell[6];
  float d1 = o0*cell[1] + o1*cell[4] + o2*cell[7];
  float d2 = o0*cell[2] + o1*cell[5] + o2*cell[8];
  float v0 = pos[3*r+0]-pos[3*c+0]+d0;
  float v1 = pos[3*r+1]-pos[3*c+1]+d1;
  float v2 = pos[3*r+2]-pos[3*c+2]+d2;
  float w = wv[e];
  float dwt = dw[e] + dC[e] * (-0.5f*(PI_F/4.0f)) * sinf(w*(PI_F/4.0f));
  float s = dwt / w;
  atomicAdd(&f[3*r+0], -v0*s); atomicAdd(&f[3*r+1], -v1*s); atomicAdd(&f[3*r+2], -v2*s);
  atomicAdd(&f[3*c+0],  v0*s); atomicAdd(&f[3*c+1],  v1*s); atomicAdd(&f[3*c+2],  v2*s);
}

// ---------------------------------------------------------------------------
extern "C" void kernel_launch(void* const* d_in, const int* in_sizes, int n_in,
                              void* d_out, int out_size, void* d_ws, size_t ws_size,
                              hipStream_t stream)
{
  const int N = in_sizes[0];
  const int E = in_sizes[2]/2;
  const int L = 6;
  const int* z        = (const int*)d_in[0];
  const float* pos    = (const float*)d_in[1];
  const int* ei       = (const int*)d_in[2];
  const float* offset = (const float*)d_in[3];
  const float* cell   = (const float*)d_in[4];
  const float* emb    = (const float*)d_in[5];
  const float* mlp_w1 = (const float*)d_in[6];
  const float* mlp_b1 = (const float*)d_in[7];
  const float* mlp_w2 = (const float*)d_in[8];
  const float* mlp_b2 = (const float*)d_in[9];
  const float* conv_w1= (const float*)d_in[10];
  const float* conv_w2= (const float*)d_in[11];
  const float* conv_b2= (const float*)d_in[12];
  const float* lin_w  = (const float*)d_in[13];
  const float* lin_b  = (const float*)d_in[14];
  const float* out1_w = (const float*)d_in[15];
  const float* out1_b = (const float*)d_in[16];
  const float* out2_w = (const float*)d_in[17];
  const float* out2_b = (const float*)d_in[18];
  float* out = (float*)d_out;

  char* wp = (char*)d_ws;
  auto alloc = [&](size_t bytes)->char*{ char* p = wp; wp += (bytes + 255) & ~(size_t)255; return p; };
  float* wbuf = (float*)alloc((size_t)E*4);
  float* Cbuf = (float*)alloc((size_t)E*4);
  float* dCb  = (float*)alloc((size_t)E*4);
  float* dwb  = (float*)alloc((size_t)E*4);
  float* xh   = (float*)alloc((size_t)L*N*128*4);
  float* mbuf = (float*)alloc((size_t)L*N*128*4);
  float* ubuf = (float*)alloc((size_t)N*64*4);
  float* hbuf = (float*)alloc((size_t)N*128*4);
  float* Gbuf = (float*)alloc((size_t)N*128*4);
  float* bufA = (float*)alloc((size_t)N*128*4);
  float* bufB = (float*)alloc((size_t)N*128*4);
  float* bufC = (float*)alloc((size_t)N*128*4);   // dxh
  float* aggb = (float*)alloc((size_t)N*128*4);
  // bf16 weight layouts
  __bf16* W1t = (__bf16*)alloc((size_t)L*8192*2);
  __bf16* W2t = (__bf16*)alloc((size_t)L*16384*2);
  __bf16* W2c = (__bf16*)alloc((size_t)L*16384*2);
  __bf16* W1c = (__bf16*)alloc((size_t)L*8192*2);

  // adaptive chunking: 3 bf16 [CH,128] edge buffers
  size_t used = (size_t)(wp - (char*)d_ws);
  long remain = (long)ws_size - (long)used - 4096;
  long CHl = remain / (3*128*2);
  long Epad = ((long)E + 127)/128*128;
  if (CHl > 65536) CHl = 65536;
  if (CHl > Epad) CHl = Epad;
  int CH = (int)((CHl/128)*128);
  if (CH < 4096) CH = 4096;
  __bf16* s1c = (__bf16*)alloc((size_t)CH*128*2);
  __bf16* Wfc = (__bf16*)alloc((size_t)CH*128*2);
  __bf16* sgc = (__bf16*)alloc((size_t)CH*128*2);
  const int nch = (E + CH - 1)/CH;

  const int egrid = (E+255)/256;
  const int ng = (N+127)/128;
  const int wtotal = L*49152;

  hipMemsetAsync(d_out, 0, (size_t)out_size*4, stream);
  convw_k<<<(wtotal+255)/256,256,0,stream>>>(mlp_w1, mlp_w2, W1t, W2t, W2c, W1c, wtotal);
  edge_geom_k<<<egrid,256,0,stream>>>(pos, ei, offset, cell, wbuf, Cbuf, E);
  embed_k<<<(N*128+255)/256,256,0,stream>>>(emb, z, hbuf, N*128);

  // ---------------- forward ----------------
  for (int i=0;i<L;i++){
    const float* b1i = mlp_b1 + (size_t)i*128;
    const float* b2i = mlp_b2 + (size_t)i*128;
    const float* cw1i= conv_w1+ (size_t)i*128*128;
    const float* cw2i= conv_w2+ (size_t)i*128*128;
    const float* cb2i= conv_b2+ (size_t)i*128;
    const float* lwi = lin_w  + (size_t)i*128*128;
    const float* lbi = lin_b  + (size_t)i*128;
    const __bf16* W1ti = W1t + (size_t)i*8192;
    const __bf16* W2ti = W2t + (size_t)i*16384;
    float* xhi = xh   + (size_t)i*N*128;
    float* mi  = mbuf + (size_t)i*N*128;

    gemm_k<128,128,false,0,false,0,false><<<ng,256,0,stream>>>(
      hbuf, 128, nullptr, nullptr, cw1i, 128, 128, nullptr, nullptr, nullptr, xhi, N);
    hipMemsetAsync(aggb, 0, (size_t)N*128*4, stream);
    for (int c=0;c<nch;c++){
      int st = c*CH; int len = E-st; if (len > CH) len = CH;
      int g = (len+63)/64;
      mgemm_k<64,4,true,1><<<g,256,0,stream>>>(
        nullptr, wbuf+st, W1ti, b1i, nullptr, s1c, nullptr, len);
      mgemm_k<128,0,true,0><<<g,256,0,stream>>>(
        s1c, nullptr, W2ti, b2i, nullptr, Wfc, nullptr, len);
      scatter_fw_k<<<(len+3)/4,256,0,stream>>>(xhi, Wfc, Cbuf, ei, st, E, aggb, len);
    }
    gemm_k<128,128,false,0,true,0,false><<<ng,256,0,stream>>>(
      aggb, 128, nullptr, nullptr, cw2i, 128, 128, cb2i, nullptr, nullptr, mi, N);
    gemm_k<128,128,false,1,true,0,true><<<ng,256,0,stream>>>(
      mi, 128, nullptr, nullptr, lwi, 128, 128, lbi, hbuf, nullptr, hbuf, N);
  }

  // head: u = h@o1+b ; E = sum ssp(u)@o2 + N*o2b ; G = (o2*sig(u))@o1^T
  gemm_k<128,64,false,0,true,0,false><<<ng,256,0,stream>>>(
    hbuf, 128, nullptr, nullptr, out1_w, 128, 64, out1_b, nullptr, nullptr, ubuf, N);
  head_k<<<(N+255)/256,256,0,stream>>>(ubuf, out2_w, out2_b, out, N);
  gemm_k<64,128,true,3,false,0,false><<<ng,256,0,stream>>>(
    ubuf, 64, nullptr, out2_w, out1_w, 64, 128, nullptr, nullptr, nullptr, Gbuf, N);

  // ---------------- backward ----------------
  for (int i=L-1;i>=0;i--){
    const float* b1i = mlp_b1 + (size_t)i*128;
    const float* b2i = mlp_b2 + (size_t)i*128;
    const float* cw1i= conv_w1+ (size_t)i*128*128;
    const float* cw2i= conv_w2+ (size_t)i*128*128;
    const float* lwi = lin_w  + (size_t)i*128*128;
    const __bf16* W1ti = W1t + (size_t)i*8192;
    const __bf16* W2ti = W2t + (size_t)i*16384;
    const __bf16* W2ci = W2c + (size_t)i*16384;
    const __bf16* W1ci = W1c + (size_t)i*8192;
    float* xhi = xh   + (size_t)i*N*128;
    float* mi  = mbuf + (size_t)i*N*128;
    int first = (i==L-1) ? 0 : 1;

    gemm_k<128,128,true,0,false,0,false><<<ng,256,0,stream>>>(
      Gbuf, 128, nullptr, nullptr, lwi, 128, 128, nullptr, nullptr, nullptr, bufA, N);
    gemm_k<128,128,true,2,false,0,false><<<ng,256,0,stream>>>(
      bufA, 128, mi, nullptr, cw2i, 128, 128, nullptr, nullptr, nullptr, bufB, N);
    hipMemsetAsync(bufC, 0, (size_t)N*128*4, stream);
    for (int c=0;c<nch;c++){
      int st = c*CH; int len = E-st; if (len > CH) len = CH;
      int g = (len+63)/64;
      int g128 = (len+127)/128;
      // recompute s1 (ssp) + sig(t1)
      mgemm_k<64,4,true,3><<<g,256,0,stream>>>(
        nullptr, wbuf+st, W1ti, b1i, nullptr, s1c, sgc, len);
      // recompute Wf
      mgemm_k<128,0,true,0><<<g,256,0,stream>>>(
        s1c, nullptr, W2ti, b2i, nullptr, Wfc, nullptr, len);
      // dxh scatter + dC + dWf (in place)
      edge_bwd_k<<<(len+3)/4,256,0,stream>>>(bufB, xhi, Wfc, Cbuf, ei, st, E, bufC, dCb, len, first);
      // dt1 = (dWf @ W2^T) * sig(t1) -> s1c (reused)
      mgemm_k<128,0,false,2><<<g,256,0,stream>>>(
        Wfc, nullptr, W2ci, nullptr, sgc, s1c, nullptr, len);
      // dw (+)= contract(dt1 @ W1^T, d ea/d w)
      gemm_dw_m<<<g128,256,0,stream>>>(s1c, W1ci, wbuf+st, dwb+st, len, first);
    }
    gemm_k<128,128,true,0,false,0,true><<<ng,256,0,stream>>>(
      bufC, 128, nullptr, nullptr, cw1i, 128, 128, nullptr, Gbuf, nullptr, Gbuf, N);
  }

  force_k<<<egrid,256,0,stream>>>(dwb, dCb, wbuf, pos, ei, offset, cell, out+1, E);
}

// Round 5
// 4447.320 us; speedup vs baseline: 2.4878x; 1.7877x over previous
//
#include <hip/hip_runtime.h>
#include <math.h>

#define LN2F 0.69314718055994530942f
#define PI_F 3.14159265358979323846f
constexpr float DMU = 4.0f/49.0f;          // gaussian spacing, linspace(0,4,50)
constexpr float GC  = -0.5f/(DMU*DMU);     // smearing coeff

typedef __bf16 bf16x8 __attribute__((ext_vector_type(8)));
typedef float  f32x4  __attribute__((ext_vector_type(4)));

__device__ __forceinline__ float sspf(float x){
  return fmaxf(x, 0.f) + log1pf(expf(-fabsf(x))) - LN2F;
}
__device__ __forceinline__ float sigf(float x){ return 1.f/(1.f+expf(-x)); }

// ---------------------------------------------------------------------------
// fp32 GEMM (node-level): out[M,NN] = epi( A'[M,KK] @ B[KK,NN] )
// ---------------------------------------------------------------------------
template<int KK,int NN,bool TRB,int ATR,bool BIAS,int OTR,bool RES>
__global__ __launch_bounds__(256) void gemm_k(
    const float* __restrict__ A, int lda,
    const float* __restrict__ aux, const float* __restrict__ auxvec,
    const float* __restrict__ B, int Kreal, int Nreal,
    const float* __restrict__ bias, const float* __restrict__ res,
    const float* __restrict__ oaux, float* __restrict__ out, int M)
{
  constexpr int TM = 128, BK = 32;
  constexpr int TX = (NN==128)?16:8;
  constexpr int RT = (NN==128)?8:4;
  __shared__ float As[BK][TM+4];
  __shared__ float Bs[BK][NN+4];
  const int t = threadIdx.x;
  const int tx = t % TX, ty = t / TX;
  const int m0 = blockIdx.x * TM;
  float acc[RT][8];
  #pragma unroll
  for (int i=0;i<RT;i++)
    #pragma unroll
    for (int j=0;j<8;j++) acc[i][j]=0.f;

  for (int kc=0; kc<KK; kc+=BK){
    #pragma unroll
    for (int j=0;j<4;j++){
      int p = t + j*256;
      int m = p >> 3;
      int kv = (p & 7) << 2;
      float4 v = make_float4(0.f,0.f,0.f,0.f);
      if (m0+m < M){
        v = *(const float4*)(A + (size_t)(m0+m)*lda + kc + kv);
        if constexpr (ATR==1){ v.x=sspf(v.x); v.y=sspf(v.y); v.z=sspf(v.z); v.w=sspf(v.w); }
        else if constexpr (ATR==2){
          float4 av = *(const float4*)(aux + (size_t)(m0+m)*lda + kc + kv);
          v.x*=sigf(av.x); v.y*=sigf(av.y); v.z*=sigf(av.z); v.w*=sigf(av.w);
        }
        else if constexpr (ATR==3){
          int kg = kc+kv;
          v.x = auxvec[kg+0]*sigf(v.x); v.y = auxvec[kg+1]*sigf(v.y);
          v.z = auxvec[kg+2]*sigf(v.z); v.w = auxvec[kg+3]*sigf(v.w);
        }
      }
      As[kv+0][m]=v.x; As[kv+1][m]=v.y; As[kv+2][m]=v.z; As[kv+3][m]=v.w;
    }
    if constexpr (!TRB){
      #pragma unroll
      for (int j=0;j<(BK*NN)/1024;j++){
        int p = t + j*256;
        int k = p / (NN/4);
        int nv = (p % (NN/4)) << 2;
        float4 v = make_float4(0.f,0.f,0.f,0.f);
        if (kc + k < Kreal) v = *(const float4*)(B + (size_t)(kc+k)*NN + nv);
        *(float4*)&Bs[k][nv] = v;
      }
    } else {
      #pragma unroll
      for (int j=0;j<(BK*NN)/1024;j++){
        int p = t + j*256;
        int n = p >> 3;
        int kv = (p & 7) << 2;
        float4 v = make_float4(0.f,0.f,0.f,0.f);
        if (n < Nreal) v = *(const float4*)(B + (size_t)n*KK + kc + kv);
        Bs[kv+0][n]=v.x; Bs[kv+1][n]=v.y; Bs[kv+2][n]=v.z; Bs[kv+3][n]=v.w;
      }
    }
    __syncthreads();
    #pragma unroll
    for (int k=0;k<BK;k++){
      float a[RT], b[8];
      #pragma unroll
      for (int i=0;i<RT;i+=4) *(float4*)&a[i] = *(const float4*)&As[k][ty*RT+i];
      *(float4*)&b[0] = *(const float4*)&Bs[k][tx*8];
      *(float4*)&b[4] = *(const float4*)&Bs[k][tx*8+4];
      #pragma unroll
      for (int i=0;i<RT;i++)
        #pragma unroll
        for (int j=0;j<8;j++)
          acc[i][j] = fmaf(a[i], b[j], acc[i][j]);
    }
    __syncthreads();
  }
  #pragma unroll
  for (int i=0;i<RT;i++){
    int r = m0 + ty*RT + i;
    if (r < M){
      float vo[8];
      #pragma unroll
      for (int j=0;j<8;j++){
        float v = acc[i][j];
        int c = tx*8 + j;
        if constexpr (BIAS) v += bias[c];
        if constexpr (OTR==1) v = sspf(v);
        else if constexpr (OTR==2) v *= sigf(oaux[(size_t)r*NN + c]);
        if constexpr (RES) v += res[(size_t)r*NN + c];
        vo[j] = v;
      }
      *(float4*)(out + (size_t)r*NN + tx*8)     = make_float4(vo[0],vo[1],vo[2],vo[3]);
      *(float4*)(out + (size_t)r*NN + tx*8 + 4) = make_float4(vo[4],vo[5],vo[6],vo[7]);
    }
  }
}

// ---------------------------------------------------------------------------
// Fused FORWARD edge kernel: per 64-edge block
//   ea(w) -> s1=ssp(ea@W1+b1) -> Wf=s1@W2+b2 -> agg[col] += xh[row]*Wf*C
// No global intermediates. 4 waves; wave = 16-row m-tile x 8 n-tiles (16x16x32).
// ---------------------------------------------------------------------------
__global__ __launch_bounds__(256) void fwd_edge_k(
    const float* __restrict__ wv, const float* __restrict__ Cv,
    const int* __restrict__ ei, int E,
    const __bf16* __restrict__ W1t, const float* __restrict__ b1,
    const __bf16* __restrict__ W2t, const float* __restrict__ b2,
    const float* __restrict__ xh, float* __restrict__ agg)
{
  __shared__ __align__(16) __bf16 W2s[128][136];   // 34.8 KB (pad 8: 2-way free)
  __shared__ __align__(16) __bf16 s1t[64][136];    // 17.4 KB
  __shared__ float wrow[64], Ce[64];
  __shared__ int rowi[64], coli[64];
  const int t = threadIdx.x;
  const int e0 = blockIdx.x*64;

  #pragma unroll
  for (int it=0; it<8; ++it){
    int p = t + it*256;
    int row = p >> 4;
    int ko = (p & 15)*8;
    *(uint4*)&W2s[row][ko] = *(const uint4*)(W2t + (size_t)row*128 + ko);
  }
  if (t < 64){
    int e = e0 + t;
    bool ok = e < E;
    wrow[t] = ok ? wv[e] : 0.f;
    Ce[t]   = ok ? Cv[e] : 0.f;
    rowi[t] = ok ? ei[e] : 0;
    coli[t] = ok ? ei[E+e] : 0;
  }
  __syncthreads();

  const int wid = t>>6, lane = t&63, quad = lane>>4, ln = lane&15;
  f32x4 acc[8];
  #pragma unroll
  for (int nt=0;nt<8;nt++) acc[nt] = (f32x4){0.f,0.f,0.f,0.f};

  // ---- GEMM1: t1 = ea @ W1 ----
  const float wa = wrow[wid*16 + ln];
  #pragma unroll
  for (int ks=0; ks<64; ks+=32){
    bf16x8 a;
    #pragma unroll
    for (int j=0;j<8;j++){
      int k = ks + quad*8 + j;
      float d = wa - (float)k*DMU;
      a[j] = (k<50) ? (__bf16)__expf(GC*d*d) : (__bf16)0.f;
    }
    #pragma unroll
    for (int nt=0; nt<8; nt++){
      bf16x8 b = *(const bf16x8*)(W1t + (size_t)(nt*16+ln)*64 + ks + quad*8);
      acc[nt] = __builtin_amdgcn_mfma_f32_16x16x32_bf16(a, b, acc[nt], 0, 0, 0);
    }
  }
  // s1 = ssp(t1+b1) -> LDS transpose
  #pragma unroll
  for (int nt=0; nt<8; nt++){
    int c = nt*16 + ln;
    float bb = b1[c];
    #pragma unroll
    for (int reg=0; reg<4; reg++){
      int r = wid*16 + quad*4 + reg;
      s1t[r][c] = (__bf16)sspf(acc[nt][reg] + bb);
    }
  }
  __syncthreads();

  // ---- GEMM2: Wf = s1 @ W2 ----
  #pragma unroll
  for (int nt=0;nt<8;nt++) acc[nt] = (f32x4){0.f,0.f,0.f,0.f};
  #pragma unroll
  for (int ks=0; ks<128; ks+=32){
    bf16x8 a = *(const bf16x8*)&s1t[wid*16 + ln][ks + quad*8];
    #pragma unroll
    for (int nt=0; nt<8; nt++){
      bf16x8 b = *(const bf16x8*)&W2s[nt*16 + ln][ks + quad*8];
      acc[nt] = __builtin_amdgcn_mfma_f32_16x16x32_bf16(a, b, acc[nt], 0, 0, 0);
    }
  }

  // ---- scatter: agg[col] += xh[row]*(Wf+b2)*C ----
  #pragma unroll
  for (int reg=0; reg<4; reg++){
    int r = wid*16 + quad*4 + reg;
    int e = e0 + r;
    if (e < E){
      float ce = Ce[r];
      size_t ri = (size_t)rowi[r]*128;
      size_t ci = (size_t)coli[r]*128;
      #pragma unroll
      for (int nt=0; nt<8; nt++){
        int c = nt*16 + ln;
        float wf = acc[nt][reg] + b2[c];
        atomicAdd(&agg[ci + c], xh[ri + c]*ce*wf);
      }
    }
  }
}

// ---------------------------------------------------------------------------
// Fused BACKWARD edge kernel: per 64-edge block
//   recompute t1/sig/s1 -> Wf -> (dC, dxh-scatter, dWf) -> dt1=dWf@W2^T*sig
//   -> dea=dt1@W1^T -> dw contraction.
// ---------------------------------------------------------------------------
__global__ __launch_bounds__(256) void bwd_edge_k(
    const float* __restrict__ wv, const float* __restrict__ Cv,
    const int* __restrict__ ei, int E,
    const __bf16* __restrict__ W1t, const float* __restrict__ b1,
    const __bf16* __restrict__ W2t, const float* __restrict__ b2,
    const __bf16* __restrict__ W2c, const __bf16* __restrict__ W1c,
    const float* __restrict__ dagg, const float* __restrict__ xh,
    float* __restrict__ dxh, float* __restrict__ dC, float* __restrict__ dw,
    int accum)
{
  __shared__ __align__(16) __bf16 Ws[128][136];    // W2t, later W2c
  __shared__ __align__(16) __bf16 tb[64][136];     // s1t -> dWft -> dt1t
  __shared__ float wrow[64], Ce[64];
  __shared__ int rowi[64], coli[64];
  const int t = threadIdx.x;
  const int e0 = blockIdx.x*64;

  #pragma unroll
  for (int it=0; it<8; ++it){
    int p = t + it*256;
    int row = p >> 4;
    int ko = (p & 15)*8;
    *(uint4*)&Ws[row][ko] = *(const uint4*)(W2t + (size_t)row*128 + ko);
  }
  if (t < 64){
    int e = e0 + t;
    bool ok = e < E;
    wrow[t] = ok ? wv[e] : 0.f;
    Ce[t]   = ok ? Cv[e] : 0.f;
    rowi[t] = ok ? ei[e] : 0;
    coli[t] = ok ? ei[E+e] : 0;
  }
  __syncthreads();

  const int wid = t>>6, lane = t&63, quad = lane>>4, ln = lane&15;
  f32x4 acc[8];
  float sig[8][4];
  #pragma unroll
  for (int nt=0;nt<8;nt++) acc[nt] = (f32x4){0.f,0.f,0.f,0.f};

  // ---- GEMM1: t1 = ea @ W1 ; keep sig(t1), store ssp(t1) ----
  const float wa = wrow[wid*16 + ln];
  #pragma unroll
  for (int ks=0; ks<64; ks+=32){
    bf16x8 a;
    #pragma unroll
    for (int j=0;j<8;j++){
      int k = ks + quad*8 + j;
      float d = wa - (float)k*DMU;
      a[j] = (k<50) ? (__bf16)__expf(GC*d*d) : (__bf16)0.f;
    }
    #pragma unroll
    for (int nt=0; nt<8; nt++){
      bf16x8 b = *(const bf16x8*)(W1t + (size_t)(nt*16+ln)*64 + ks + quad*8);
      acc[nt] = __builtin_amdgcn_mfma_f32_16x16x32_bf16(a, b, acc[nt], 0, 0, 0);
    }
  }
  #pragma unroll
  for (int nt=0; nt<8; nt++){
    int c = nt*16 + ln;
    float bb = b1[c];
    #pragma unroll
    for (int reg=0; reg<4; reg++){
      int r = wid*16 + quad*4 + reg;
      float t1 = acc[nt][reg] + bb;
      sig[nt][reg] = sigf(t1);
      tb[r][c] = (__bf16)sspf(t1);
    }
  }
  __syncthreads();

  // ---- GEMM2: Wf = s1 @ W2 ----
  #pragma unroll
  for (int nt=0;nt<8;nt++) acc[nt] = (f32x4){0.f,0.f,0.f,0.f};
  #pragma unroll
  for (int ks=0; ks<128; ks+=32){
    bf16x8 a = *(const bf16x8*)&tb[wid*16 + ln][ks + quad*8];
    #pragma unroll
    for (int nt=0; nt<8; nt++){
      bf16x8 b = *(const bf16x8*)&Ws[nt*16 + ln][ks + quad*8];
      acc[nt] = __builtin_amdgcn_mfma_f32_16x16x32_bf16(a, b, acc[nt], 0, 0, 0);
    }
  }
  __syncthreads();   // all reads of tb (s1) and Ws (W2t) done

  // ---- edge step: dC, dxh scatter, dWf -> tb ; restage Ws <- W2c ----
  #pragma unroll
  for (int reg=0; reg<4; reg++){
    int r = wid*16 + quad*4 + reg;
    int e = e0 + r;
    float dcp = 0.f;
    if (e < E){
      float ce = Ce[r];
      size_t ri = (size_t)rowi[r]*128;
      size_t ci = (size_t)coli[r]*128;
      #pragma unroll
      for (int nt=0; nt<8; nt++){
        int c = nt*16 + ln;
        float wf = acc[nt][reg] + b2[c];
        float da = dagg[ci + c];
        float xv = xh[ri + c];
        dcp += da*xv*wf;
        atomicAdd(&dxh[ri + c], da*ce*wf);
        tb[r][c] = (__bf16)(da*xv*ce);
      }
    } else {
      #pragma unroll
      for (int nt=0; nt<8; nt++) tb[r][nt*16+ln] = (__bf16)0.f;
    }
    dcp += __shfl_xor(dcp, 1);
    dcp += __shfl_xor(dcp, 2);
    dcp += __shfl_xor(dcp, 4);
    dcp += __shfl_xor(dcp, 8);
    if (ln==0 && e < E) dC[e] = accum ? (dC[e]+dcp) : dcp;
  }
  #pragma unroll
  for (int it=0; it<8; ++it){
    int p = t + it*256;
    int row = p >> 4;
    int ko = (p & 15)*8;
    *(uint4*)&Ws[row][ko] = *(const uint4*)(W2c + (size_t)row*128 + ko);
  }
  __syncthreads();

  // ---- GEMM3: dt1 = (dWf @ W2^T) * sig ----
  #pragma unroll
  for (int nt=0;nt<8;nt++) acc[nt] = (f32x4){0.f,0.f,0.f,0.f};
  #pragma unroll
  for (int ks=0; ks<128; ks+=32){
    bf16x8 a = *(const bf16x8*)&tb[wid*16 + ln][ks + quad*8];
    #pragma unroll
    for (int nt=0; nt<8; nt++){
      bf16x8 b = *(const bf16x8*)&Ws[nt*16 + ln][ks + quad*8];
      acc[nt] = __builtin_amdgcn_mfma_f32_16x16x32_bf16(a, b, acc[nt], 0, 0, 0);
    }
  }
  __syncthreads();   // all reads of tb (dWf) done
  #pragma unroll
  for (int nt=0; nt<8; nt++){
    int c = nt*16 + ln;
    #pragma unroll
    for (int reg=0; reg<4; reg++){
      int r = wid*16 + quad*4 + reg;
      tb[r][c] = (__bf16)(acc[nt][reg] * sig[nt][reg]);
    }
  }
  __syncthreads();

  // ---- GEMM4: dea = dt1 @ W1^T ; contract to dw ----
  #pragma unroll
  for (int nt=0;nt<4;nt++) acc[nt] = (f32x4){0.f,0.f,0.f,0.f};
  #pragma unroll
  for (int ks=0; ks<128; ks+=32){
    bf16x8 a = *(const bf16x8*)&tb[wid*16 + ln][ks + quad*8];
    #pragma unroll
    for (int nt=0; nt<4; nt++){
      bf16x8 b = *(const bf16x8*)(W1c + (size_t)(nt*16+ln)*128 + ks + quad*8);
      acc[nt] = __builtin_amdgcn_mfma_f32_16x16x32_bf16(a, b, acc[nt], 0, 0, 0);
    }
  }
  #pragma unroll
  for (int reg=0; reg<4; reg++){
    int r = wid*16 + quad*4 + reg;
    int e = e0 + r;
    float w = wrow[r];
    float s = 0.f;
    #pragma unroll
    for (int nt=0; nt<4; nt++){
      int c = nt*16 + ln;
      if (c < 50){
        float d = w - (float)c*DMU;
        s += acc[nt][reg] * (2.f*GC*d) * __expf(GC*d*d);
      }
    }
    s += __shfl_xor(s, 1);
    s += __shfl_xor(s, 2);
    s += __shfl_xor(s, 4);
    s += __shfl_xor(s, 8);
    if (ln==0 && e < E) dw[e] = accum ? (dw[e]+s) : s;
  }
}

// ---------------------------------------------------------------------------
// one-time bf16 weight conversion
// ---------------------------------------------------------------------------
__global__ void convw_k(const float* __restrict__ w1, const float* __restrict__ w2,
                        __bf16* __restrict__ W1t, __bf16* __restrict__ W2t,
                        __bf16* __restrict__ W2c, __bf16* __restrict__ W1c, int total)
{
  int idx = blockIdx.x*256 + threadIdx.x;
  if (idx >= total) return;
  int l = idx / 49152;
  int r = idx % 49152;
  if (r < 8192){                       // W1t[n][k] = w1[k][n], k<50
    int n = r / 64, k = r % 64;
    float v = (k<50) ? w1[(size_t)l*6400 + k*128 + n] : 0.f;
    W1t[(size_t)l*8192 + r] = (__bf16)v;
  } else if (r < 24576){               // W2t[n][k] = w2[k][n]
    int r2 = r - 8192;
    int n = r2 / 128, k = r2 % 128;
    W2t[(size_t)l*16384 + r2] = (__bf16)w2[(size_t)l*16384 + k*128 + n];
  } else if (r < 40960){               // W2c = w2 (elementwise)
    int r2 = r - 24576;
    W2c[(size_t)l*16384 + r2] = (__bf16)w2[(size_t)l*16384 + r2];
  } else {                             // W1c[n][k] = w1[n][k], n<50
    int r2 = r - 40960;
    int n = r2 / 128, k = r2 % 128;
    float v = (n<50) ? w1[(size_t)l*6400 + n*128 + k] : 0.f;
    W1c[(size_t)l*8192 + r2] = (__bf16)v;
  }
}

// ---------------------------------------------------------------------------
__global__ void edge_geom_k(const float* __restrict__ pos, const int* __restrict__ ei,
                            const float* __restrict__ off, const float* __restrict__ cell,
                            float* __restrict__ wv, float* __restrict__ Cv, int E)
{
  int e = blockIdx.x*256 + threadIdx.x;
  if (e>=E) return;
  int r = ei[e], c = ei[E+e];
  float o0=off[3*e], o1=off[3*e+1], o2=off[3*e+2];
  float d0 = o0*cell[0] + o1*cell[3] + o2*cell[6];
  float d1 = o0*cell[1] + o1*cell[4] + o2*cell[7];
  float d2 = o0*cell[2] + o1*cell[5] + o2*cell[8];
  float v0 = pos[3*r+0]-pos[3*c+0]+d0;
  float v1 = pos[3*r+1]-pos[3*c+1]+d1;
  float v2 = pos[3*r+2]-pos[3*c+2]+d2;
  float w = sqrtf(v0*v0+v1*v1+v2*v2);
  wv[e]=w;
  Cv[e]=0.5f*cosf(w*(PI_F/4.0f)) + 0.5f;
}

__global__ void embed_k(const float* __restrict__ emb, const int* __restrict__ z,
                        float* __restrict__ h, int total){
  int i = blockIdx.x*256 + threadIdx.x;
  if (i < total){ int n=i>>7, j=i&127; h[i] = emb[(size_t)z[n]*128 + j]; }
}

// readout energy
__global__ void head_k(const float* __restrict__ u, const float* __restrict__ o2,
                       const float* __restrict__ o2b, float* __restrict__ out0, int N){
  int n = blockIdx.x*256 + threadIdx.x;
  float s = 0.f;
  if (n < N){
    #pragma unroll
    for (int k=0;k<64;k+=4){
      float4 uv = *(const float4*)(u + (size_t)n*64 + k);
      float4 ov = *(const float4*)(o2 + k);
      s += sspf(uv.x)*ov.x + sspf(uv.y)*ov.y + sspf(uv.z)*ov.z + sspf(uv.w)*ov.w;
    }
  }
  #pragma unroll
  for (int m=1;m<64;m<<=1) s += __shfl_xor(s, m);
  __shared__ float red[4];
  int lane = threadIdx.x&63, w = threadIdx.x>>6;
  if (lane==0) red[w]=s;
  __syncthreads();
  if (threadIdx.x==0){
    float tot = red[0]+red[1]+red[2]+red[3];
    if (blockIdx.x==0) tot += (float)N * o2b[0];
    atomicAdd(out0, tot);
  }
}

// forces: recompute vec, dvec = vec*(dw + dC*dCdw)/w, atomic scatter to f
__global__ void force_k(const float* __restrict__ dw, const float* __restrict__ dC,
                        const float* __restrict__ wv,
                        const float* __restrict__ pos, const int* __restrict__ ei,
                        const float* __restrict__ off, const float* __restrict__ cell,
                        float* __restrict__ f, int E)
{
  int e = blockIdx.x*256 + threadIdx.x;
  if (e>=E) return;
  int r = ei[e], c = ei[E+e];
  float o0=off[3*e], o1=off[3*e+1], o2=off[3*e+2];
  float d0 = o0*cell[0] + o1*cell[3] + o2*cell[6];
  float d1 = o0*cell[1] + o1*cell[4] + o2*cell[7];
  float d2 = o0*cell[2] + o1*cell[5] + o2*cell[8];
  float v0 = pos[3*r+0]-pos[3*c+0]+d0;
  float v1 = pos[3*r+1]-pos[3*c+1]+d1;
  float v2 = pos[3*r+2]-pos[3*c+2]+d2;
  float w = wv[e];
  float dwt = dw[e] + dC[e] * (-0.5f*(PI_F/4.0f)) * sinf(w*(PI_F/4.0f));
  float s = dwt / w;
  atomicAdd(&f[3*r+0], -v0*s); atomicAdd(&f[3*r+1], -v1*s); atomicAdd(&f[3*r+2], -v2*s);
  atomicAdd(&f[3*c+0],  v0*s); atomicAdd(&f[3*c+1],  v1*s); atomicAdd(&f[3*c+2],  v2*s);
}

// ---------------------------------------------------------------------------
extern "C" void kernel_launch(void* const* d_in, const int* in_sizes, int n_in,
                              void* d_out, int out_size, void* d_ws, size_t ws_size,
                              hipStream_t stream)
{
  const int N = in_sizes[0];
  const int E = in_sizes[2]/2;
  const int L = 6;
  const int* z        = (const int*)d_in[0];
  const float* pos    = (const float*)d_in[1];
  const int* ei       = (const int*)d_in[2];
  const float* offset = (const float*)d_in[3];
  const float* cell   = (const float*)d_in[4];
  const float* emb    = (const float*)d_in[5];
  const float* mlp_w1 = (const float*)d_in[6];
  const float* mlp_b1 = (const float*)d_in[7];
  const float* mlp_w2 = (const float*)d_in[8];
  const float* mlp_b2 = (const float*)d_in[9];
  const float* conv_w1= (const float*)d_in[10];
  const float* conv_w2= (const float*)d_in[11];
  const float* conv_b2= (const float*)d_in[12];
  const float* lin_w  = (const float*)d_in[13];
  const float* lin_b  = (const float*)d_in[14];
  const float* out1_w = (const float*)d_in[15];
  const float* out1_b = (const float*)d_in[16];
  const float* out2_w = (const float*)d_in[17];
  const float* out2_b = (const float*)d_in[18];
  float* out = (float*)d_out;

  char* wp = (char*)d_ws;
  auto alloc = [&](size_t bytes)->char*{ char* p = wp; wp += (bytes + 255) & ~(size_t)255; return p; };
  float* wbuf = (float*)alloc((size_t)E*4);
  float* Cbuf = (float*)alloc((size_t)E*4);
  float* dCb  = (float*)alloc((size_t)E*4);
  float* dwb  = (float*)alloc((size_t)E*4);
  float* xh   = (float*)alloc((size_t)L*N*128*4);
  float* mbuf = (float*)alloc((size_t)L*N*128*4);
  float* ubuf = (float*)alloc((size_t)N*64*4);
  float* hbuf = (float*)alloc((size_t)N*128*4);
  float* Gbuf = (float*)alloc((size_t)N*128*4);
  float* bufA = (float*)alloc((size_t)N*128*4);
  float* bufB = (float*)alloc((size_t)N*128*4);
  float* bufC = (float*)alloc((size_t)N*128*4);   // dxh
  float* aggb = (float*)alloc((size_t)N*128*4);
  __bf16* W1t = (__bf16*)alloc((size_t)L*8192*2);
  __bf16* W2t = (__bf16*)alloc((size_t)L*16384*2);
  __bf16* W2c = (__bf16*)alloc((size_t)L*16384*2);
  __bf16* W1c = (__bf16*)alloc((size_t)L*8192*2);

  const int egrid = (E+255)/256;
  const int eg64 = (E+63)/64;
  const int ng = (N+127)/128;
  const int wtotal = L*49152;

  hipMemsetAsync(d_out, 0, (size_t)out_size*4, stream);
  convw_k<<<(wtotal+255)/256,256,0,stream>>>(mlp_w1, mlp_w2, W1t, W2t, W2c, W1c, wtotal);
  edge_geom_k<<<egrid,256,0,stream>>>(pos, ei, offset, cell, wbuf, Cbuf, E);
  embed_k<<<(N*128+255)/256,256,0,stream>>>(emb, z, hbuf, N*128);

  // ---------------- forward ----------------
  for (int i=0;i<L;i++){
    const float* b1i = mlp_b1 + (size_t)i*128;
    const float* b2i = mlp_b2 + (size_t)i*128;
    const float* cw1i= conv_w1+ (size_t)i*128*128;
    const float* cw2i= conv_w2+ (size_t)i*128*128;
    const float* cb2i= conv_b2+ (size_t)i*128;
    const float* lwi = lin_w  + (size_t)i*128*128;
    const float* lbi = lin_b  + (size_t)i*128;
    float* xhi = xh   + (size_t)i*N*128;
    float* mi  = mbuf + (size_t)i*N*128;

    gemm_k<128,128,false,0,false,0,false><<<ng,256,0,stream>>>(
      hbuf, 128, nullptr, nullptr, cw1i, 128, 128, nullptr, nullptr, nullptr, xhi, N);
    hipMemsetAsync(aggb, 0, (size_t)N*128*4, stream);
    fwd_edge_k<<<eg64,256,0,stream>>>(
      wbuf, Cbuf, ei, E, W1t + (size_t)i*8192, b1i, W2t + (size_t)i*16384, b2i, xhi, aggb);
    gemm_k<128,128,false,0,true,0,false><<<ng,256,0,stream>>>(
      aggb, 128, nullptr, nullptr, cw2i, 128, 128, cb2i, nullptr, nullptr, mi, N);
    gemm_k<128,128,false,1,true,0,true><<<ng,256,0,stream>>>(
      mi, 128, nullptr, nullptr, lwi, 128, 128, lbi, hbuf, nullptr, hbuf, N);
  }

  // head: u = h@o1+b ; E = sum ssp(u)@o2 + N*o2b ; G = (o2*sig(u))@o1^T
  gemm_k<128,64,false,0,true,0,false><<<ng,256,0,stream>>>(
    hbuf, 128, nullptr, nullptr, out1_w, 128, 64, out1_b, nullptr, nullptr, ubuf, N);
  head_k<<<(N+255)/256,256,0,stream>>>(ubuf, out2_w, out2_b, out, N);
  gemm_k<64,128,true,3,false,0,false><<<ng,256,0,stream>>>(
    ubuf, 64, nullptr, out2_w, out1_w, 64, 128, nullptr, nullptr, nullptr, Gbuf, N);

  // ---------------- backward ----------------
  for (int i=L-1;i>=0;i--){
    const float* b1i = mlp_b1 + (size_t)i*128;
    const float* b2i = mlp_b2 + (size_t)i*128;
    const float* cw1i= conv_w1+ (size_t)i*128*128;
    const float* cw2i= conv_w2+ (size_t)i*128*128;
    const float* lwi = lin_w  + (size_t)i*128*128;
    float* xhi = xh   + (size_t)i*N*128;
    float* mi  = mbuf + (size_t)i*N*128;
    int first = (i==L-1) ? 0 : 1;

    gemm_k<128,128,true,0,false,0,false><<<ng,256,0,stream>>>(
      Gbuf, 128, nullptr, nullptr, lwi, 128, 128, nullptr, nullptr, nullptr, bufA, N);
    gemm_k<128,128,true,2,false,0,false><<<ng,256,0,stream>>>(
      bufA, 128, mi, nullptr, cw2i, 128, 128, nullptr, nullptr, nullptr, bufB, N);
    hipMemsetAsync(bufC, 0, (size_t)N*128*4, stream);
    bwd_edge_k<<<eg64,256,0,stream>>>(
      wbuf, Cbuf, ei, E,
      W1t + (size_t)i*8192, b1i, W2t + (size_t)i*16384, b2i,
      W2c + (size_t)i*16384, W1c + (size_t)i*8192,
      bufB, xhi, bufC, dCb, dwb, first);
    gemm_k<128,128,true,0,false,0,true><<<ng,256,0,stream>>>(
      bufC, 128, nullptr, nullptr, cw1i, 128, 128, nullptr, Gbuf, nullptr, Gbuf, N);
  }

  force_k<<<egrid,256,0,stream>>>(dwb, dCb, wbuf, pos, ei, offset, cell, out+1, E);
}